// Round 2
// baseline (463.296 us; speedup 1.0000x reference)
//
#include <hip/hip_runtime.h>
#include <hip/hip_bf16.h>

#define BATCH 16
#define NCAND 25200
#define NCLS 80
#define PREDC 85
#define KTOP 1000
#define MAXDET 300
#define CAP 2048
#define NBINS 1024
#define TILE_ROWS 128
#define CONF 0.45f
#define HSCALE ((float)NBINS / (1.0f - 0.45f))

// ---------------- K0: zero/init workspace (harness poisons ws once) ----------------
__global__ __launch_bounds__(256) void k_init(int* __restrict__ hist,
                                              unsigned long long* __restrict__ keys,
                                              int* __restrict__ cnt,
                                              unsigned long long* __restrict__ nzw) {
    int t = blockIdx.x * 256 + threadIdx.x;          // 128 blocks -> 32768 threads
    keys[t] = ~0ULL;                                 // 16*2048 = 32768
    if (t < BATCH * NBINS) hist[t] = 0;              // 16384
    if (t < BATCH) cnt[t] = 0;
    if (t < BATCH * 16) nzw[t] = 0ULL;
}

// ---------------- K1: per-candidate score + global histogram ----------------
__global__ __launch_bounds__(TILE_ROWS) void k_score(const float* __restrict__ pred,
                                                     float* __restrict__ score,
                                                     int* __restrict__ hist) {
    __shared__ float lds[TILE_ROWS * PREDC];
    int tile = blockIdx.x;
    int tid = threadIdx.x;
    size_t base = (size_t)tile * (TILE_ROWS * PREDC);
    const float4* src4 = (const float4*)(pred + base);
    float4* l4 = (float4*)lds;
    const int NV4 = TILE_ROWS * PREDC / 4;  // 2720
    for (int k = tid; k < NV4; k += TILE_ROWS) l4[k] = src4[k];
    __syncthreads();
    const float* row = lds + tid * PREDC;
    float obj = row[4];
    float best = -1.0f;
    #pragma unroll 8
    for (int c = 0; c < NCLS; ++c) {
        float v = row[5 + c] * obj;
        if (v > best) best = v;
    }
    bool valid = (obj > CONF) && (best > CONF);
    float s = valid ? best : -1.0f;
    int grow = tile * TILE_ROWS + tid;
    score[grow] = s;
    if (s > CONF) {
        int b = grow / NCAND;
        int bin = (int)((s - CONF) * HSCALE);
        bin = bin < 0 ? 0 : (bin > NBINS - 1 ? NBINS - 1 : bin);
        atomicAdd(&hist[b * NBINS + bin], 1);
    }
}

// ---------------- K2: per-image threshold bin via suffix scan ----------------
__global__ __launch_bounds__(256) void k_findT(const int* __restrict__ hist,
                                               int* __restrict__ Tarr) {
    int b = blockIdx.x, tid = threadIdx.x;
    __shared__ int h[NBINS];
    __shared__ int s_T;
    if (tid == 0) s_T = 0;
    #pragma unroll
    for (int k = 0; k < 4; ++k) h[tid + k * 256] = hist[b * NBINS + tid + k * 256];
    __syncthreads();
    for (int off = 1; off < NBINS; off <<= 1) {
        int tmp[4];
        #pragma unroll
        for (int k = 0; k < 4; ++k) {
            int idx = tid + k * 256;
            tmp[k] = (idx + off < NBINS) ? h[idx + off] : 0;
        }
        __syncthreads();
        #pragma unroll
        for (int k = 0; k < 4; ++k) h[tid + k * 256] += tmp[k];
        __syncthreads();
    }
    #pragma unroll
    for (int k = 0; k < 4; ++k) {
        int idx = tid + k * 256;
        int S = h[idx];
        int Sn = (idx + 1 < NBINS) ? h[idx + 1] : 0;
        if (S >= KTOP && Sn < KTOP) s_T = idx;   // unique idx (suffix monotone)
    }
    __syncthreads();
    if (tid == 0) Tarr[b] = s_T;
}

// ---------------- K3: gather survivors (bin >= T) into per-image key buffers ----
__global__ __launch_bounds__(256) void k_gather(const float* __restrict__ score,
                                                const int* __restrict__ Tarr,
                                                unsigned long long* __restrict__ keys,
                                                int* __restrict__ cnt) {
    int g = blockIdx.x * 256 + threadIdx.x;          // 403200 total
    float s = score[g];
    if (s > CONF) {
        int b = g / NCAND;
        int n = g - b * NCAND;
        int bin = (int)((s - CONF) * HSCALE);
        bin = bin < 0 ? 0 : (bin > NBINS - 1 ? NBINS - 1 : bin);
        if (bin >= Tarr[b]) {
            int pos = atomicAdd(&cnt[b], 1);
            if (pos < CAP) {
                unsigned int sb = __float_as_uint(s);
                keys[b * CAP + pos] = ((unsigned long long)(~sb) << 32) | (unsigned)n;
            }
        }
    }
}

// ---------------- K4: per-image bitonic sort (2048 keys, 1024 thr) + emit top-K ----
__global__ __launch_bounds__(1024) void k_sort(const float* __restrict__ pred,
                                               const unsigned long long* __restrict__ keys,
                                               const int* __restrict__ cnt,
                                               int* __restrict__ topidx,
                                               float* __restrict__ topsc,
                                               int* __restrict__ topcls,
                                               float* __restrict__ boxes,
                                               int* __restrict__ cntarr) {
    int b = blockIdx.x, tid = threadIdx.x;
    __shared__ unsigned long long sbuf[CAP];
    sbuf[tid] = keys[b * CAP + tid];
    sbuf[tid + 1024] = keys[b * CAP + tid + 1024];
    __syncthreads();
    // bitonic sort ascending: key = (~score_bits, idx) -> score desc, idx asc
    for (unsigned k = 2; k <= CAP; k <<= 1) {
        for (unsigned j = k >> 1; j > 0; j >>= 1) {
            #pragma unroll
            for (int q = 0; q < 2; ++q) {
                unsigned t = tid + q * 1024;
                unsigned ixj = t ^ j;
                if (ixj > t) {
                    unsigned long long a = sbuf[t], bb = sbuf[ixj];
                    if ((a > bb) == ((t & k) == 0)) { sbuf[t] = bb; sbuf[ixj] = a; }
                }
            }
            __syncthreads();
        }
    }
    int C2 = cnt[b]; if (C2 > CAP) C2 = CAP;
    if (tid < KTOP) {
        int o = b * KTOP + tid;
        if (tid < C2) {
            unsigned long long key = sbuf[tid];
            int n = (int)(key & 0xFFFFFFFFULL);
            float s = __uint_as_float(~(unsigned int)(key >> 32));
            const float* row = pred + ((size_t)b * NCAND + n) * PREDC;
            float cx = row[0], cy = row[1], w = row[2], h = row[3];
            float obj = row[4];
            float best = -1.0f; int bj = 0;
            for (int c = 0; c < NCLS; ++c) {
                float v = row[5 + c] * obj;
                if (v > best) { best = v; bj = c; }
            }
            topidx[o] = n; topsc[o] = s; topcls[o] = bj;
            ((float4*)boxes)[o] = make_float4(cx - w * 0.5f, cy - h * 0.5f,
                                              cx + w * 0.5f, cy + h * 0.5f);
        } else {
            topidx[o] = 0; topsc[o] = -1.0f; topcls[o] = 0;
            ((float4*)boxes)[o] = make_float4(0.f, 0.f, 0.f, 0.f);
        }
    }
    if (tid == 0) cntarr[b] = C2 < KTOP ? C2 : KTOP;
}

// ---------------- K5: IoU bitmask (j>i, iou>thr) + nz bitmap ----------------
__global__ __launch_bounds__(256) void k_iou(const float* __restrict__ boxes,
                                             unsigned long long* __restrict__ M,
                                             unsigned long long* __restrict__ nzw) {
    #pragma clang fp contract(off)
    int g = blockIdx.x * 256 + threadIdx.x;   // 16*1000*16 = 256000
    int w = g & 15;
    int bi = g >> 4;                          // 0..15999
    int i = bi % KTOP;
    int b = bi / KTOP;
    const float4* bx = (const float4*)boxes + (size_t)b * KTOP;
    float4 A = bx[i];
    float areaA = (A.z - A.x) * (A.w - A.y);
    unsigned long long word = 0;
    int j0 = w * 64;
    int jend = j0 + 64; if (jend > KTOP) jend = KTOP;
    #pragma unroll 4
    for (int j = j0; j < jend; ++j) {
        float4 Bb = bx[j];
        float areaB = (Bb.z - Bb.x) * (Bb.w - Bb.y);
        float lx = fmaxf(A.x, Bb.x), ly = fmaxf(A.y, Bb.y);
        float rx = fminf(A.z, Bb.z), ry = fminf(A.w, Bb.w);
        float ww = rx - lx; ww = ww > 0.f ? ww : 0.f;
        float hh = ry - ly; hh = hh > 0.f ? hh : 0.f;
        float inter = ww * hh;
        float denom = ((areaA + areaB) - inter) + 1e-9f;
        float iou = inter / denom;
        if (j > i && iou > 0.45f) word |= 1ULL << (j - j0);
    }
    M[(size_t)bi * 16 + w] = word;
    if (word) atomicOr(&nzw[b * 16 + (i >> 6)], 1ULL << (i & 63));
}

// ---------------- K6: sequential greedy NMS over nz rows ----------------
__global__ __launch_bounds__(64) void k_nms(const unsigned long long* __restrict__ M,
                                            const unsigned long long* __restrict__ nzw,
                                            const int* __restrict__ cntarr,
                                            unsigned long long* __restrict__ keepw) {
    int b = blockIdx.x, l = threadIdx.x;
    __shared__ unsigned long long s_nzw[16];
    __shared__ int nzlist[1024];
    __shared__ int s_nnz;
    if (l < 16) s_nzw[l] = nzw[b * 16 + l];
    __syncthreads();
    if (l < 16) {
        int pre = 0;
        for (int u = 0; u < l; ++u) pre += __popcll(s_nzw[u]);
        unsigned long long wv = s_nzw[l];
        int ofs = pre;
        while (wv) {
            int bit = __builtin_ctzll(wv);
            nzlist[ofs++] = l * 64 + bit;
            wv &= wv - 1;
        }
        if (l == 15) s_nnz = ofs;
    }
    __syncthreads();
    int nnz = s_nnz;
    int kc0 = cntarr[b];
    int w = l & 15;
    int lo = w * 64;
    unsigned long long supp;
    if (kc0 <= lo) supp = ~0ULL;
    else if (kc0 >= lo + 64) supp = 0ULL;
    else supp = (~0ULL) << (kc0 - lo);
    const unsigned long long* Mb = M + (size_t)b * KTOP * 16;
    int i_next = 0; unsigned long long w_next = 0;
    if (nnz > 0) { i_next = nzlist[0]; w_next = Mb[(size_t)i_next * 16 + w]; }
    for (int k = 0; k < nnz; ++k) {
        int i = i_next;
        unsigned long long mw = w_next;
        if (k + 1 < nnz) { i_next = nzlist[k + 1]; w_next = Mb[(size_t)i_next * 16 + w]; }
        int src = i >> 6;
        int slo = __shfl((int)(supp & 0xFFFFFFFFULL), src);
        int shi = __shfl((int)(supp >> 32), src);
        unsigned long long sw = ((unsigned long long)(unsigned)shi << 32) | (unsigned)slo;
        bool alive = ((sw >> (i & 63)) & 1ULL) == 0ULL;
        if (alive) supp |= mw;   // wave-uniform condition
    }
    if (l < 16) keepw[b * 16 + l] = ~supp;
}

// ---------------- K7: compact keep -> top-300 outputs ----------------
__global__ __launch_bounds__(256) void k_out(const float* __restrict__ logits,
                                             const unsigned long long* __restrict__ keepw,
                                             const int* __restrict__ topidx,
                                             const float* __restrict__ topsc,
                                             const int* __restrict__ topcls,
                                             const float* __restrict__ boxes,
                                             float* __restrict__ out) {
    int b = blockIdx.x, tid = threadIdx.x;
    __shared__ int kept_r[MAXDET];
    __shared__ int kept_n[MAXDET];
    __shared__ int s_kc;
    __shared__ unsigned long long s_kw[16];
    if (tid < 16) s_kw[tid] = keepw[b * 16 + tid];
    __syncthreads();
    if (tid < 16) {
        int pre = 0;
        for (int u = 0; u < tid; ++u) pre += __popcll(s_kw[u]);
        unsigned long long wv = s_kw[tid];
        int rank = pre;
        while (wv) {
            int bit = __builtin_ctzll(wv);
            if (rank < MAXDET) kept_r[rank] = tid * 64 + bit;
            rank++;
            wv &= wv - 1;
        }
        if (tid == 15) s_kc = rank < MAXDET ? rank : MAXDET;
    }
    __syncthreads();
    int kc = s_kc;
    for (int s = tid; s < MAXDET; s += 256)
        if (s < kc) kept_n[s] = topidx[b * KTOP + kept_r[s]];
    __syncthreads();
    float* det = out;                                        // [16][300][6]
    float* mask_o = out + BATCH * MAXDET * 6;                // [16][300]
    float* lgo = out + BATCH * MAXDET * 6 + BATCH * MAXDET;  // [16][300][80]
    for (int idx = tid; idx < MAXDET * 6; idx += 256) {
        int s = idx / 6, col = idx % 6;
        float v = 0.f;
        if (s < kc) {
            int o = b * KTOP + kept_r[s];
            if (col < 4) v = boxes[o * 4 + col];
            else if (col == 4) v = topsc[o];
            else v = (float)topcls[o];
        }
        det[b * MAXDET * 6 + idx] = v;
    }
    for (int s = tid; s < MAXDET; s += 256)
        mask_o[b * MAXDET + s] = (s < kc) ? 1.0f : 0.0f;
    for (int idx = tid; idx < MAXDET * NCLS; idx += 256) {
        int s = idx / NCLS, c = idx % NCLS;
        float v = 0.f;
        if (s < kc) v = logits[((size_t)b * NCAND + kept_n[s]) * NCLS + c];
        lgo[b * MAXDET * NCLS + idx] = v;
    }
}

extern "C" void kernel_launch(void* const* d_in, const int* in_sizes, int n_in,
                              void* d_out, int out_size, void* d_ws, size_t ws_size,
                              hipStream_t stream) {
    (void)in_sizes; (void)n_in; (void)out_size; (void)ws_size;
    const float* pred = (const float*)d_in[0];
    const float* logits = (const float*)d_in[1];
    float* out = (float*)d_out;
    char* ws = (char*)d_ws;

    // workspace layout (bytes)
    float* score  = (float*)(ws + 0);                              // 1,612,800
    int*   hist   = (int*)(ws + 1612800);                          // 65,536
    int*   Tarr   = (int*)(ws + 1678336);                          // 64
    int*   cnt    = (int*)(ws + 1678400);                          // 64
    int*   cntarr = (int*)(ws + 1678464);                          // 64
    unsigned long long* keys = (unsigned long long*)(ws + 1678528); // 262,144
    int*   topidx = (int*)(ws + 1940672);                          // 64,000
    float* topsc  = (float*)(ws + 2004672);                        // 64,000
    int*   topcls = (int*)(ws + 2068672);                          // 64,000
    float* boxes  = (float*)(ws + 2132672);                        // 256,000 (16B aligned)
    unsigned long long* M     = (unsigned long long*)(ws + 2388672); // 2,048,000
    unsigned long long* nzw   = (unsigned long long*)(ws + 4436672); // 2,048
    unsigned long long* keepw = (unsigned long long*)(ws + 4438720); // 2,048

    const int nrows = BATCH * NCAND;                 // 403200
    k_init<<<128, 256, 0, stream>>>(hist, keys, cnt, nzw);
    k_score<<<nrows / TILE_ROWS, TILE_ROWS, 0, stream>>>(pred, score, hist);
    k_findT<<<BATCH, 256, 0, stream>>>(hist, Tarr);
    k_gather<<<nrows / 256, 256, 0, stream>>>(score, Tarr, keys, cnt);
    k_sort<<<BATCH, 1024, 0, stream>>>(pred, keys, cnt, topidx, topsc, topcls, boxes, cntarr);
    k_iou<<<(BATCH * KTOP * 16) / 256, 256, 0, stream>>>(boxes, M, nzw);
    k_nms<<<BATCH, 64, 0, stream>>>(M, nzw, cntarr, keepw);
    k_out<<<BATCH, 256, 0, stream>>>(logits, keepw, topidx, topsc, topcls, boxes, out);
}

// Round 3
// 197.525 us; speedup vs baseline: 2.3455x; 2.3455x over previous
//
#include <hip/hip_runtime.h>
#include <hip/hip_bf16.h>

#define BATCH 16
#define NCAND 25200
#define NCLS 80
#define PREDC 85
#define KTOP 1000
#define MAXDET 300
#define CAP 2048
#define NBINS 1024
#define TILE_ROWS 128
#define CONF 0.45f
#define HSCALE ((float)NBINS / (1.0f - 0.45f))
#define CNT_STRIDE 16   // ints; 64B between per-image counters

typedef unsigned long long ull;

// ---------------- K0: zero/init workspace ----------------
__global__ __launch_bounds__(256) void k_init(int* __restrict__ hist,
                                              ull* __restrict__ keys,
                                              int* __restrict__ cnt,
                                              ull* __restrict__ nzw) {
    int t = blockIdx.x * 256 + threadIdx.x;          // 128 blocks -> 32768 threads
    keys[t] = ~0ULL;                                 // 16*2048 = 32768
    if (t < BATCH * NBINS) hist[t] = 0;              // 16384
    if (t < BATCH * CNT_STRIDE) cnt[t] = 0;
    if (t < BATCH * 16) nzw[t] = 0ULL;
}

// ---------------- K1: per-candidate score + global histogram ----------------
__global__ __launch_bounds__(256) void k_score(const float* __restrict__ pred,
                                               float* __restrict__ score,
                                               int* __restrict__ hist) {
    __shared__ float lds[TILE_ROWS * PREDC];   // 43,520 B
    int tile = blockIdx.x;
    int tid = threadIdx.x;
    size_t base = (size_t)tile * (TILE_ROWS * PREDC);
    const float4* src4 = (const float4*)(pred + base);
    float4* l4 = (float4*)lds;
    const int NV4 = TILE_ROWS * PREDC / 4;  // 2720
    for (int k = tid; k < NV4; k += 256) l4[k] = src4[k];
    __syncthreads();
    if (tid < TILE_ROWS) {
        const float* row = lds + tid * PREDC;
        float obj = row[4];
        float best = -1.0f;
        #pragma unroll 8
        for (int c = 0; c < NCLS; ++c) {
            float v = row[5 + c] * obj;
            if (v > best) best = v;
        }
        bool valid = (obj > CONF) && (best > CONF);
        float s = valid ? best : -1.0f;
        int grow = tile * TILE_ROWS + tid;
        score[grow] = s;
        if (s > CONF) {
            int b = grow / NCAND;
            int bin = (int)((s - CONF) * HSCALE);
            bin = bin < 0 ? 0 : (bin > NBINS - 1 ? NBINS - 1 : bin);
            atomicAdd(&hist[b * NBINS + bin], 1);
        }
    }
}

// ---------------- K2: per-image threshold bin via suffix scan ----------------
__global__ __launch_bounds__(256) void k_findT(const int* __restrict__ hist,
                                               int* __restrict__ Tarr) {
    int b = blockIdx.x, tid = threadIdx.x;
    __shared__ int h[NBINS];
    __shared__ int s_T;
    if (tid == 0) s_T = 0;
    #pragma unroll
    for (int k = 0; k < 4; ++k) h[tid + k * 256] = hist[b * NBINS + tid + k * 256];
    __syncthreads();
    for (int off = 1; off < NBINS; off <<= 1) {
        int tmp[4];
        #pragma unroll
        for (int k = 0; k < 4; ++k) {
            int idx = tid + k * 256;
            tmp[k] = (idx + off < NBINS) ? h[idx + off] : 0;
        }
        __syncthreads();
        #pragma unroll
        for (int k = 0; k < 4; ++k) h[tid + k * 256] += tmp[k];
        __syncthreads();
    }
    #pragma unroll
    for (int k = 0; k < 4; ++k) {
        int idx = tid + k * 256;
        int S = h[idx];
        int Sn = (idx + 1 < NBINS) ? h[idx + 1] : 0;
        if (S >= KTOP && Sn < KTOP) s_T = idx;   // unique (suffix monotone)
    }
    __syncthreads();
    if (tid == 0) Tarr[b] = s_T;
}

// ---------------- K3: gather survivors, one atomic per block ----------------
__global__ __launch_bounds__(256) void k_gather(const float* __restrict__ score,
                                                const int* __restrict__ Tarr,
                                                ull* __restrict__ keys,
                                                int* __restrict__ cnt) {
    int b = blockIdx.y;
    int n = blockIdx.x * 256 + threadIdx.x;
    int tid = threadIdx.x;
    __shared__ int wbase[4];
    __shared__ int sT;
    if (tid == 0) sT = Tarr[b];
    __syncthreads();
    bool want = false;
    float s = 0.0f;
    if (n < NCAND) {
        s = score[b * NCAND + n];
        if (s > CONF) {
            int bin = (int)((s - CONF) * HSCALE);
            bin = bin < 0 ? 0 : (bin > NBINS - 1 ? NBINS - 1 : bin);
            want = (bin >= sT);
        }
    }
    ull m = __ballot(want);
    int lane = tid & 63, widx = tid >> 6;
    if (lane == 0) wbase[widx] = __popcll(m);
    __syncthreads();
    if (tid == 0) {
        int t0 = wbase[0], t1 = wbase[1], t2 = wbase[2], t3 = wbase[3];
        int tot = t0 + t1 + t2 + t3;
        int b0 = tot ? atomicAdd(&cnt[b * CNT_STRIDE], tot) : 0;
        wbase[0] = b0; wbase[1] = b0 + t0; wbase[2] = b0 + t0 + t1; wbase[3] = b0 + t0 + t1 + t2;
    }
    __syncthreads();
    if (want) {
        int pos = wbase[widx] + __popcll(m & ((1ULL << lane) - 1ULL));
        if (pos < CAP) {
            unsigned int sb = __float_as_uint(s);
            keys[b * CAP + pos] = ((ull)(~sb) << 32) | (unsigned)n;
        }
    }
}

// ---------------- K4: per-image bitonic sort (2048 keys) + emit top-K ----------
__global__ __launch_bounds__(1024) void k_sort(const float* __restrict__ pred,
                                               const ull* __restrict__ keys,
                                               const int* __restrict__ cnt,
                                               int* __restrict__ topidx,
                                               float* __restrict__ topsc,
                                               int* __restrict__ topcls,
                                               float* __restrict__ boxes) {
    int b = blockIdx.x, tid = threadIdx.x;
    __shared__ ull sbuf[CAP];
    sbuf[tid] = keys[b * CAP + tid];
    sbuf[tid + 1024] = keys[b * CAP + tid + 1024];
    __syncthreads();
    for (unsigned k = 2; k <= CAP; k <<= 1) {
        for (unsigned j = k >> 1; j > 0; j >>= 1) {
            #pragma unroll
            for (int q = 0; q < 2; ++q) {
                unsigned t = tid + q * 1024;
                unsigned ixj = t ^ j;
                if (ixj > t) {
                    ull a = sbuf[t], bb = sbuf[ixj];
                    if ((a > bb) == ((t & k) == 0)) { sbuf[t] = bb; sbuf[ixj] = a; }
                }
            }
            __syncthreads();
        }
    }
    int C2 = cnt[b * CNT_STRIDE]; if (C2 > CAP) C2 = CAP;
    if (tid < KTOP) {
        int o = b * KTOP + tid;
        if (tid < C2) {
            ull key = sbuf[tid];
            int n = (int)(key & 0xFFFFFFFFULL);
            float s = __uint_as_float(~(unsigned int)(key >> 32));
            const float* row = pred + ((size_t)b * NCAND + n) * PREDC;
            float cx = row[0], cy = row[1], w = row[2], h = row[3];
            float obj = row[4];
            float best = -1.0f; int bj = 0;
            for (int c = 0; c < NCLS; ++c) {
                float v = row[5 + c] * obj;
                if (v > best) { best = v; bj = c; }
            }
            topidx[o] = n; topsc[o] = s; topcls[o] = bj;
            ((float4*)boxes)[o] = make_float4(cx - w * 0.5f, cy - h * 0.5f,
                                              cx + w * 0.5f, cy + h * 0.5f);
        } else {
            topidx[o] = 0; topsc[o] = -1.0f; topcls[o] = 0;
            ((float4*)boxes)[o] = make_float4(0.f, 0.f, 0.f, 0.f);
        }
    }
}

// ---------------- K5: IoU bitmask (j>i, iou>thr) + nz bitmap ----------------
__global__ __launch_bounds__(256) void k_iou(const float* __restrict__ boxes,
                                             ull* __restrict__ M,
                                             ull* __restrict__ nzw) {
    #pragma clang fp contract(off)
    int g = blockIdx.x * 256 + threadIdx.x;   // 16*1000*16 = 256000
    int w = g & 15;
    int bi = g >> 4;                          // 0..15999
    int i = bi % KTOP;
    int b = bi / KTOP;
    const float4* bx = (const float4*)boxes + (size_t)b * KTOP;
    float4 A = bx[i];
    float areaA = (A.z - A.x) * (A.w - A.y);
    ull word = 0;
    int j0 = w * 64;
    int jend = j0 + 64; if (jend > KTOP) jend = KTOP;
    #pragma unroll 4
    for (int j = j0; j < jend; ++j) {
        float4 Bb = bx[j];
        float areaB = (Bb.z - Bb.x) * (Bb.w - Bb.y);
        float lx = fmaxf(A.x, Bb.x), ly = fmaxf(A.y, Bb.y);
        float rx = fminf(A.z, Bb.z), ry = fminf(A.w, Bb.w);
        float ww = rx - lx; ww = ww > 0.f ? ww : 0.f;
        float hh = ry - ly; hh = hh > 0.f ? hh : 0.f;
        float inter = ww * hh;
        float denom = ((areaA + areaB) - inter) + 1e-9f;
        float iou = inter / denom;
        if (j > i && iou > 0.45f) word |= 1ULL << (j - j0);
    }
    M[(size_t)bi * 16 + w] = word;
    if (word) atomicOr(&nzw[b * 16 + (i >> 6)], 1ULL << (i & 63));
}

// ---------------- K6: sequential greedy NMS, depth-8 prefetch ----------------
__global__ __launch_bounds__(64) void k_nms(const ull* __restrict__ M,
                                            const ull* __restrict__ nzw,
                                            const int* __restrict__ cnt,
                                            ull* __restrict__ keepw) {
    int b = blockIdx.x, l = threadIdx.x;
    __shared__ ull s_nzw[16];
    __shared__ int nzlist[1024];
    __shared__ int s_nnz;
    if (l < 16) s_nzw[l] = nzw[b * 16 + l];
    __syncthreads();
    if (l < 16) {
        int pre = 0;
        for (int u = 0; u < l; ++u) pre += __popcll(s_nzw[u]);
        ull wv = s_nzw[l];
        int ofs = pre;
        while (wv) {
            int bit = __builtin_ctzll(wv);
            nzlist[ofs++] = l * 64 + bit;
            wv &= wv - 1;
        }
        if (l == 15) s_nnz = ofs;
    }
    __syncthreads();
    int nnz = s_nnz;
    int kc0 = cnt[b * CNT_STRIDE]; if (kc0 > KTOP) kc0 = KTOP;
    int w = l & 15;
    int lo = w * 64;
    ull supp;
    if (kc0 <= lo) supp = ~0ULL;
    else if (kc0 >= lo + 64) supp = 0ULL;
    else supp = (~0ULL) << (kc0 - lo);
    const ull* Mb = M + (size_t)b * KTOP * 16;
    // depth-8 software pipeline over nz rows
    int ibuf[8]; ull wbuf[8];
    #pragma unroll
    for (int d = 0; d < 8; ++d) {
        int q = (d < nnz) ? nzlist[d] : 0;
        ibuf[d] = q; wbuf[d] = Mb[(size_t)q * 16 + w];
    }
    for (int k = 0; k < nnz; k += 8) {
        int nib[8]; ull nwb[8];
        #pragma unroll
        for (int d = 0; d < 8; ++d) {
            int q2 = k + 8 + d;
            int q = (q2 < nnz) ? nzlist[q2] : 0;
            nib[d] = q; nwb[d] = Mb[(size_t)q * 16 + w];
        }
        #pragma unroll
        for (int d = 0; d < 8; ++d) {
            if (k + d < nnz) {
                int i = ibuf[d]; ull mw = wbuf[d];
                int src = i >> 6;
                int slo = __shfl((int)(supp & 0xFFFFFFFFULL), src);
                int shi = __shfl((int)(supp >> 32), src);
                ull sw = ((ull)(unsigned)shi << 32) | (unsigned)slo;
                bool alive = ((sw >> (i & 63)) & 1ULL) == 0ULL;
                if (alive) supp |= mw;   // wave-uniform condition
            }
        }
        #pragma unroll
        for (int d = 0; d < 8; ++d) { ibuf[d] = nib[d]; wbuf[d] = nwb[d]; }
    }
    if (l < 16) keepw[b * 16 + l] = ~supp;
}

// ---------------- K7: compact keep -> top-300 outputs ----------------
__global__ __launch_bounds__(256) void k_out(const float* __restrict__ logits,
                                             const ull* __restrict__ keepw,
                                             const int* __restrict__ topidx,
                                             const float* __restrict__ topsc,
                                             const int* __restrict__ topcls,
                                             const float* __restrict__ boxes,
                                             float* __restrict__ out) {
    int b = blockIdx.x, tid = threadIdx.x;
    __shared__ int kept_r[MAXDET];
    __shared__ int kept_n[MAXDET];
    __shared__ int s_kc;
    __shared__ ull s_kw[16];
    if (tid < 16) s_kw[tid] = keepw[b * 16 + tid];
    __syncthreads();
    if (tid < 16) {
        int pre = 0;
        for (int u = 0; u < tid; ++u) pre += __popcll(s_kw[u]);
        ull wv = s_kw[tid];
        int rank = pre;
        while (wv) {
            int bit = __builtin_ctzll(wv);
            if (rank < MAXDET) kept_r[rank] = tid * 64 + bit;
            rank++;
            wv &= wv - 1;
        }
        if (tid == 15) s_kc = rank < MAXDET ? rank : MAXDET;
    }
    __syncthreads();
    int kc = s_kc;
    for (int s = tid; s < MAXDET; s += 256)
        if (s < kc) kept_n[s] = topidx[b * KTOP + kept_r[s]];
    __syncthreads();
    float* det = out;                                        // [16][300][6]
    float* mask_o = out + BATCH * MAXDET * 6;                // [16][300]
    float* lgo = out + BATCH * MAXDET * 6 + BATCH * MAXDET;  // [16][300][80]
    for (int idx = tid; idx < MAXDET * 6; idx += 256) {
        int s = idx / 6, col = idx % 6;
        float v = 0.f;
        if (s < kc) {
            int o = b * KTOP + kept_r[s];
            if (col < 4) v = boxes[o * 4 + col];
            else if (col == 4) v = topsc[o];
            else v = (float)topcls[o];
        }
        det[b * MAXDET * 6 + idx] = v;
    }
    for (int s = tid; s < MAXDET; s += 256)
        mask_o[b * MAXDET + s] = (s < kc) ? 1.0f : 0.0f;
    for (int idx = tid; idx < MAXDET * NCLS; idx += 256) {
        int s = idx / NCLS, c = idx % NCLS;
        float v = 0.f;
        if (s < kc) v = logits[((size_t)b * NCAND + kept_n[s]) * NCLS + c];
        lgo[b * MAXDET * NCLS + idx] = v;
    }
}

extern "C" void kernel_launch(void* const* d_in, const int* in_sizes, int n_in,
                              void* d_out, int out_size, void* d_ws, size_t ws_size,
                              hipStream_t stream) {
    (void)in_sizes; (void)n_in; (void)out_size; (void)ws_size;
    const float* pred = (const float*)d_in[0];
    const float* logits = (const float*)d_in[1];
    float* out = (float*)d_out;
    char* ws = (char*)d_ws;

    // workspace layout (bytes). Region A is time-shared:
    //   score/hist/Tarr live K0..K3; M (2,048,000) overlays them, live K5..K6.
    float* score  = (float*)(ws + 0);                    // 1,612,800
    int*   hist   = (int*)(ws + 1612800);                // 65,536
    int*   Tarr   = (int*)(ws + 1678336);                // 64
    ull*   M      = (ull*)(ws + 0);                      // 2,048,000 (overlay)
    ull*   keys   = (ull*)(ws + 2048000);                // 262,144
    int*   cnt    = (int*)(ws + 2310144);                // 1,024 (16 imgs x 64B)
    int*   topidx = (int*)(ws + 2311168);                // 64,000
    float* topsc  = (float*)(ws + 2375168);              // 64,000
    int*   topcls = (int*)(ws + 2439168);                // 64,000
    float* boxes  = (float*)(ws + 2503168);              // 256,000 (16B aligned)
    ull*   nzw    = (ull*)(ws + 2759168);                // 2,048
    ull*   keepw  = (ull*)(ws + 2761216);                // 2,048  (total 2,763,264)

    const int nrows = BATCH * NCAND;                     // 403200
    k_init<<<128, 256, 0, stream>>>(hist, keys, cnt, nzw);
    k_score<<<nrows / TILE_ROWS, 256, 0, stream>>>(pred, score, hist);
    k_findT<<<BATCH, 256, 0, stream>>>(hist, Tarr);
    k_gather<<<dim3((NCAND + 255) / 256, BATCH), 256, 0, stream>>>(score, Tarr, keys, cnt);
    k_sort<<<BATCH, 1024, 0, stream>>>(pred, keys, cnt, topidx, topsc, topcls, boxes);
    k_iou<<<(BATCH * KTOP * 16) / 256, 256, 0, stream>>>(boxes, M, nzw);
    k_nms<<<BATCH, 64, 0, stream>>>(M, nzw, cnt, keepw);
    k_out<<<BATCH, 256, 0, stream>>>(logits, keepw, topidx, topsc, topcls, boxes, out);
}

// Round 4
// 181.197 us; speedup vs baseline: 2.5569x; 1.0901x over previous
//
#include <hip/hip_runtime.h>
#include <hip/hip_bf16.h>

#define BATCH 16
#define NCAND 25200
#define NCLS 80
#define PREDC 85
#define KTOP 1000
#define MAXDET 300
#define CAP 2048
#define NBINS 1024
#define TILE_ROWS 128
#define CONF 0.45f
#define HSCALE ((float)NBINS / (1.0f - 0.45f))
#define CNT_STRIDE 16   // ints; 64B between per-image counters
#define NMS_CHUNK 440

typedef unsigned long long ull;

// ---------------- K0: zero/init workspace ----------------
__global__ __launch_bounds__(256) void k_init(int* __restrict__ hist,
                                              ull* __restrict__ keys,
                                              int* __restrict__ cnt,
                                              ull* __restrict__ nzw) {
    int t = blockIdx.x * 256 + threadIdx.x;          // 128 blocks -> 32768 threads
    keys[t] = ~0ULL;                                 // 16*2048 = 32768
    if (t < BATCH * NBINS) hist[t] = 0;              // 16384
    if (t < BATCH * CNT_STRIDE) cnt[t] = 0;
    if (t < BATCH * 16) nzw[t] = 0ULL;
}

// ---------------- K1: per-candidate score + global histogram ----------------
__global__ __launch_bounds__(256) void k_score(const float* __restrict__ pred,
                                               float* __restrict__ score,
                                               int* __restrict__ hist) {
    __shared__ float lds[TILE_ROWS * PREDC];   // 43,520 B
    int tile = blockIdx.x;
    int tid = threadIdx.x;
    size_t base = (size_t)tile * (TILE_ROWS * PREDC);
    const float4* src4 = (const float4*)(pred + base);
    float4* l4 = (float4*)lds;
    const int NV4 = TILE_ROWS * PREDC / 4;  // 2720
    for (int k = tid; k < NV4; k += 256) l4[k] = src4[k];
    __syncthreads();
    if (tid < TILE_ROWS) {
        const float* row = lds + tid * PREDC;
        float obj = row[4];
        float best = -1.0f;
        #pragma unroll 8
        for (int c = 0; c < NCLS; ++c) {
            float v = row[5 + c] * obj;
            if (v > best) best = v;
        }
        bool valid = (obj > CONF) && (best > CONF);
        float s = valid ? best : -1.0f;
        int grow = tile * TILE_ROWS + tid;
        score[grow] = s;
        if (s > CONF) {
            int b = grow / NCAND;
            int bin = (int)((s - CONF) * HSCALE);
            bin = bin < 0 ? 0 : (bin > NBINS - 1 ? NBINS - 1 : bin);
            atomicAdd(&hist[b * NBINS + bin], 1);
        }
    }
}

// ---------------- K2: per-image threshold bin via suffix scan ----------------
__global__ __launch_bounds__(256) void k_findT(const int* __restrict__ hist,
                                               int* __restrict__ Tarr) {
    int b = blockIdx.x, tid = threadIdx.x;
    __shared__ int h[NBINS];
    __shared__ int s_T;
    if (tid == 0) s_T = 0;
    #pragma unroll
    for (int k = 0; k < 4; ++k) h[tid + k * 256] = hist[b * NBINS + tid + k * 256];
    __syncthreads();
    for (int off = 1; off < NBINS; off <<= 1) {
        int tmp[4];
        #pragma unroll
        for (int k = 0; k < 4; ++k) {
            int idx = tid + k * 256;
            tmp[k] = (idx + off < NBINS) ? h[idx + off] : 0;
        }
        __syncthreads();
        #pragma unroll
        for (int k = 0; k < 4; ++k) h[tid + k * 256] += tmp[k];
        __syncthreads();
    }
    #pragma unroll
    for (int k = 0; k < 4; ++k) {
        int idx = tid + k * 256;
        int S = h[idx];
        int Sn = (idx + 1 < NBINS) ? h[idx + 1] : 0;
        if (S >= KTOP && Sn < KTOP) s_T = idx;   // unique (suffix monotone)
    }
    __syncthreads();
    if (tid == 0) Tarr[b] = s_T;
}

// ---------------- K3: gather survivors, one atomic per block ----------------
__global__ __launch_bounds__(256) void k_gather(const float* __restrict__ score,
                                                const int* __restrict__ Tarr,
                                                ull* __restrict__ keys,
                                                int* __restrict__ cnt) {
    int b = blockIdx.y;
    int n = blockIdx.x * 256 + threadIdx.x;
    int tid = threadIdx.x;
    __shared__ int wbase[4];
    __shared__ int sT;
    if (tid == 0) sT = Tarr[b];
    __syncthreads();
    bool want = false;
    float s = 0.0f;
    if (n < NCAND) {
        s = score[b * NCAND + n];
        if (s > CONF) {
            int bin = (int)((s - CONF) * HSCALE);
            bin = bin < 0 ? 0 : (bin > NBINS - 1 ? NBINS - 1 : bin);
            want = (bin >= sT);
        }
    }
    ull m = __ballot(want);
    int lane = tid & 63, widx = tid >> 6;
    if (lane == 0) wbase[widx] = __popcll(m);
    __syncthreads();
    if (tid == 0) {
        int t0 = wbase[0], t1 = wbase[1], t2 = wbase[2], t3 = wbase[3];
        int tot = t0 + t1 + t2 + t3;
        int b0 = tot ? atomicAdd(&cnt[b * CNT_STRIDE], tot) : 0;
        wbase[0] = b0; wbase[1] = b0 + t0; wbase[2] = b0 + t0 + t1; wbase[3] = b0 + t0 + t1 + t2;
    }
    __syncthreads();
    if (want) {
        int pos = wbase[widx] + __popcll(m & ((1ULL << lane) - 1ULL));
        if (pos < CAP) {
            unsigned int sb = __float_as_uint(s);
            keys[b * CAP + pos] = ((ull)(~sb) << 32) | (unsigned)n;
        }
    }
}

// ---------------- K4: per-image bitonic sort (P=1024 or 2048) + emit top-K ----
__global__ __launch_bounds__(1024) void k_sort(const float* __restrict__ pred,
                                               const ull* __restrict__ keys,
                                               const int* __restrict__ cnt,
                                               int* __restrict__ topidx,
                                               float* __restrict__ topsc,
                                               int* __restrict__ topcls,
                                               float* __restrict__ boxes) {
    int b = blockIdx.x, tid = threadIdx.x;
    __shared__ ull sbuf[CAP];
    __shared__ int s_C2;
    if (tid == 0) {
        int c = cnt[b * CNT_STRIDE];
        s_C2 = c > CAP ? CAP : c;
    }
    __syncthreads();
    int C2 = s_C2;
    unsigned P = (C2 <= 1024) ? 1024u : 2048u;
    sbuf[tid] = keys[b * CAP + tid];
    if (P > 1024) sbuf[tid + 1024] = keys[b * CAP + tid + 1024];
    __syncthreads();
    for (unsigned k = 2; k <= P; k <<= 1) {
        for (unsigned j = k >> 1; j > 0; j >>= 1) {
            for (unsigned t = tid; t < P; t += 1024) {
                unsigned ixj = t ^ j;
                if (ixj > t) {
                    ull a = sbuf[t], bb = sbuf[ixj];
                    if ((a > bb) == ((t & k) == 0)) { sbuf[t] = bb; sbuf[ixj] = a; }
                }
            }
            __syncthreads();
        }
    }
    if (tid < KTOP) {
        int o = b * KTOP + tid;
        if (tid < C2) {
            ull key = sbuf[tid];
            int n = (int)(key & 0xFFFFFFFFULL);
            float s = __uint_as_float(~(unsigned int)(key >> 32));
            const float* row = pred + ((size_t)b * NCAND + n) * PREDC;
            float cx = row[0], cy = row[1], w = row[2], h = row[3];
            float obj = row[4];
            float best = -1.0f; int bj = 0;
            for (int c = 0; c < NCLS; ++c) {
                float v = row[5 + c] * obj;
                if (v > best) { best = v; bj = c; }
            }
            topidx[o] = n; topsc[o] = s; topcls[o] = bj;
            ((float4*)boxes)[o] = make_float4(cx - w * 0.5f, cy - h * 0.5f,
                                              cx + w * 0.5f, cy + h * 0.5f);
        } else {
            topidx[o] = 0; topsc[o] = -1.0f; topcls[o] = 0;
            ((float4*)boxes)[o] = make_float4(0.f, 0.f, 0.f, 0.f);
        }
    }
}

// ---------------- K5: IoU bitmask (j>i, iou>thr) + nz bitmap ----------------
__global__ __launch_bounds__(256) void k_iou(const float* __restrict__ boxes,
                                             ull* __restrict__ M,
                                             ull* __restrict__ nzw) {
    #pragma clang fp contract(off)
    int g = blockIdx.x * 256 + threadIdx.x;   // 16*1000*16 = 256000
    int w = g & 15;
    int bi = g >> 4;                          // 0..15999
    int i = bi % KTOP;
    int b = bi / KTOP;
    int j0 = w * 64;
    if (j0 + 63 <= i) {                       // whole block strictly j<=i -> zero
        M[(size_t)bi * 16 + w] = 0ULL;
        return;
    }
    const float4* bx = (const float4*)boxes + (size_t)b * KTOP;
    float4 A = bx[i];
    float areaA = (A.z - A.x) * (A.w - A.y);
    ull word = 0;
    int jend = j0 + 64; if (jend > KTOP) jend = KTOP;
    #pragma unroll 4
    for (int j = j0; j < jend; ++j) {
        float4 Bb = bx[j];
        float areaB = (Bb.z - Bb.x) * (Bb.w - Bb.y);
        float lx = fmaxf(A.x, Bb.x), ly = fmaxf(A.y, Bb.y);
        float rx = fminf(A.z, Bb.z), ry = fminf(A.w, Bb.w);
        float ww = rx - lx; ww = ww > 0.f ? ww : 0.f;
        float hh = ry - ly; hh = hh > 0.f ? hh : 0.f;
        float inter = ww * hh;
        float denom = ((areaA + areaB) - inter) + 1e-9f;
        float iou = inter / denom;
        if (j > i && iou > 0.45f) word |= 1ULL << (j - j0);
    }
    M[(size_t)bi * 16 + w] = word;
    if (word) atomicOr(&nzw[b * 16 + (i >> 6)], 1ULL << (i & 63));
}

// ---------------- K6: NMS (LDS-staged M rows) + top-300 outputs ----------------
__global__ __launch_bounds__(256) void k_nms_out(const ull* __restrict__ M,
                                                 const ull* __restrict__ nzw,
                                                 const int* __restrict__ cnt,
                                                 const float* __restrict__ logits,
                                                 const int* __restrict__ topidx,
                                                 const float* __restrict__ topsc,
                                                 const int* __restrict__ topcls,
                                                 const float* __restrict__ boxes,
                                                 float* __restrict__ out) {
    __shared__ ull mrows[NMS_CHUNK * 16];   // 56,320 B
    __shared__ int nzlist[KTOP];            // 4,000 B
    __shared__ ull s_nzw[16];
    __shared__ ull s_keep[16];
    __shared__ int s_nnz;
    __shared__ int kept_r[MAXDET];
    __shared__ int kept_n[MAXDET];
    __shared__ int s_kc;
    int b = blockIdx.x, tid = threadIdx.x;
    if (tid < 16) s_nzw[tid] = nzw[b * 16 + tid];
    __syncthreads();
    if (tid < 16) {
        int pre = 0;
        for (int u = 0; u < tid; ++u) pre += __popcll(s_nzw[u]);
        ull wv = s_nzw[tid];
        int ofs = pre;
        while (wv) {
            int bit = __builtin_ctzll(wv);
            nzlist[ofs++] = tid * 64 + bit;
            wv &= wv - 1;
        }
        if (tid == 15) s_nnz = ofs;
    }
    __syncthreads();
    int nnz = s_nnz;
    int kc0 = cnt[b * CNT_STRIDE]; if (kc0 > KTOP) kc0 = KTOP;
    const ull* Mb = M + (size_t)b * KTOP * 16;
    ull supp = 0;
    {
        int w = tid & 15, lo = w * 64;
        if (kc0 <= lo) supp = ~0ULL;
        else if (kc0 >= lo + 64) supp = 0ULL;
        else supp = (~0ULL) << (kc0 - lo);
    }
    for (int c0 = 0; c0 < nnz; c0 += NMS_CHUNK) {
        int cn = nnz - c0; if (cn > NMS_CHUNK) cn = NMS_CHUNK;
        // cooperative bulk load of chunk rows into LDS (coalesced 128B/row)
        for (int u = tid; u < cn * 16; u += 256)
            mrows[u] = Mb[(size_t)nzlist[c0 + (u >> 4)] * 16 + (u & 15)];
        __syncthreads();
        if (tid < 64) {
            int w = tid & 15;
            for (int k = 0; k < cn; k += 4) {
                ull mb[4]; int ii[4];
                #pragma unroll
                for (int d = 0; d < 4; ++d) {
                    int kk = k + d; kk = kk < cn ? kk : cn - 1;
                    mb[d] = mrows[kk * 16 + w];
                    ii[d] = nzlist[c0 + kk];
                }
                #pragma unroll
                for (int d = 0; d < 4; ++d) {
                    if (k + d < cn) {
                        int i = ii[d];
                        int src = i >> 6;
                        int slo = __shfl((int)(supp & 0xFFFFFFFFULL), src);
                        int shi = __shfl((int)(supp >> 32), src);
                        ull sw = ((ull)(unsigned)shi << 32) | (unsigned)slo;
                        if (((sw >> (i & 63)) & 1ULL) == 0ULL) supp |= mb[d];
                    }
                }
            }
        }
        __syncthreads();
    }
    if (tid < 16) s_keep[tid] = ~supp;   // lanes 0..15 hold words 0..15
    __syncthreads();
    // ---- output phase (all 256 threads) ----
    if (tid < 16) {
        int pre = 0;
        for (int u = 0; u < tid; ++u) pre += __popcll(s_keep[u]);
        ull wv = s_keep[tid];
        int rank = pre;
        while (wv) {
            int bit = __builtin_ctzll(wv);
            if (rank < MAXDET) kept_r[rank] = tid * 64 + bit;
            rank++;
            wv &= wv - 1;
        }
        if (tid == 15) s_kc = rank < MAXDET ? rank : MAXDET;
    }
    __syncthreads();
    int kc = s_kc;
    for (int s = tid; s < MAXDET; s += 256)
        if (s < kc) kept_n[s] = topidx[b * KTOP + kept_r[s]];
    __syncthreads();
    float* det = out;                                        // [16][300][6]
    float* mask_o = out + BATCH * MAXDET * 6;                // [16][300]
    float* lgo = out + BATCH * MAXDET * 6 + BATCH * MAXDET;  // [16][300][80]
    for (int idx = tid; idx < MAXDET * 6; idx += 256) {
        int s = idx / 6, col = idx % 6;
        float v = 0.f;
        if (s < kc) {
            int o = b * KTOP + kept_r[s];
            if (col < 4) v = boxes[o * 4 + col];
            else if (col == 4) v = topsc[o];
            else v = (float)topcls[o];
        }
        det[b * MAXDET * 6 + idx] = v;
    }
    for (int s = tid; s < MAXDET; s += 256)
        mask_o[b * MAXDET + s] = (s < kc) ? 1.0f : 0.0f;
    for (int idx = tid; idx < MAXDET * NCLS; idx += 256) {
        int s = idx / NCLS, c = idx % NCLS;
        float v = 0.f;
        if (s < kc) v = logits[((size_t)b * NCAND + kept_n[s]) * NCLS + c];
        lgo[b * MAXDET * NCLS + idx] = v;
    }
}

extern "C" void kernel_launch(void* const* d_in, const int* in_sizes, int n_in,
                              void* d_out, int out_size, void* d_ws, size_t ws_size,
                              hipStream_t stream) {
    (void)in_sizes; (void)n_in; (void)out_size; (void)ws_size;
    const float* pred = (const float*)d_in[0];
    const float* logits = (const float*)d_in[1];
    float* out = (float*)d_out;
    char* ws = (char*)d_ws;

    // workspace layout (bytes). Region A is time-shared:
    //   score/hist/Tarr live K0..K3; M (2,048,000) overlays them, live K5..K6.
    float* score  = (float*)(ws + 0);                    // 1,612,800
    int*   hist   = (int*)(ws + 1612800);                // 65,536
    int*   Tarr   = (int*)(ws + 1678336);                // 64
    ull*   M      = (ull*)(ws + 0);                      // 2,048,000 (overlay)
    ull*   keys   = (ull*)(ws + 2048000);                // 262,144
    int*   cnt    = (int*)(ws + 2310144);                // 1,024 (16 imgs x 64B)
    int*   topidx = (int*)(ws + 2311168);                // 64,000
    float* topsc  = (float*)(ws + 2375168);              // 64,000
    int*   topcls = (int*)(ws + 2439168);                // 64,000
    float* boxes  = (float*)(ws + 2503168);              // 256,000 (16B aligned)
    ull*   nzw    = (ull*)(ws + 2759168);                // 2,048  (total 2,761,216)

    const int nrows = BATCH * NCAND;                     // 403200
    k_init<<<128, 256, 0, stream>>>(hist, keys, cnt, nzw);
    k_score<<<nrows / TILE_ROWS, 256, 0, stream>>>(pred, score, hist);
    k_findT<<<BATCH, 256, 0, stream>>>(hist, Tarr);
    k_gather<<<dim3((NCAND + 255) / 256, BATCH), 256, 0, stream>>>(score, Tarr, keys, cnt);
    k_sort<<<BATCH, 1024, 0, stream>>>(pred, keys, cnt, topidx, topsc, topcls, boxes);
    k_iou<<<(BATCH * KTOP * 16) / 256, 256, 0, stream>>>(boxes, M, nzw);
    k_nms_out<<<BATCH, 256, 0, stream>>>(M, nzw, cnt, logits, topidx, topsc, topcls, boxes, out);
}

// Round 5
// 176.131 us; speedup vs baseline: 2.6304x; 1.0288x over previous
//
#include <hip/hip_runtime.h>
#include <hip/hip_bf16.h>

#define BATCH 16
#define NCAND 25200
#define NCLS 80
#define PREDC 85
#define KTOP 1000
#define MAXDET 300
#define CAP 2048
#define NBINS 1024
#define TILE_ROWS 128
#define CONF 0.45f
#define HSCALE ((float)NBINS / (1.0f - 0.45f))
#define CNT_STRIDE 16   // ints; 64B between per-image counters
#define NMS_CHUNK 440

typedef unsigned long long ull;

// ---------------- K0: zero/init workspace ----------------
__global__ __launch_bounds__(256) void k_init(int* __restrict__ hist,
                                              ull* __restrict__ keys,
                                              int* __restrict__ cnt,
                                              ull* __restrict__ nzw) {
    int t = blockIdx.x * 256 + threadIdx.x;          // 128 blocks -> 32768 threads
    keys[t] = ~0ULL;                                 // 16*2048 = 32768
    if (t < BATCH * NBINS) hist[t] = 0;              // 16384
    if (t < BATCH * CNT_STRIDE) cnt[t] = 0;
    if (t < BATCH * 16) nzw[t] = 0ULL;
}

// ---------------- K1: per-candidate score + global histogram ----------------
__global__ __launch_bounds__(256) void k_score(const float* __restrict__ pred,
                                               float* __restrict__ score,
                                               int* __restrict__ hist) {
    __shared__ float lds[TILE_ROWS * PREDC];   // 43,520 B
    int tile = blockIdx.x;
    int tid = threadIdx.x;
    size_t base = (size_t)tile * (TILE_ROWS * PREDC);
    const float4* src4 = (const float4*)(pred + base);
    float4* l4 = (float4*)lds;
    const int NV4 = TILE_ROWS * PREDC / 4;  // 2720
    for (int k = tid; k < NV4; k += 256) l4[k] = src4[k];
    __syncthreads();
    if (tid < TILE_ROWS) {
        const float* row = lds + tid * PREDC;
        float obj = row[4];
        float best = -1.0f;
        #pragma unroll 8
        for (int c = 0; c < NCLS; ++c) {
            float v = row[5 + c] * obj;
            if (v > best) best = v;
        }
        bool valid = (obj > CONF) && (best > CONF);
        float s = valid ? best : -1.0f;
        int grow = tile * TILE_ROWS + tid;
        score[grow] = s;
        if (s > CONF) {
            int b = grow / NCAND;
            int bin = (int)((s - CONF) * HSCALE);
            bin = bin < 0 ? 0 : (bin > NBINS - 1 ? NBINS - 1 : bin);
            atomicAdd(&hist[b * NBINS + bin], 1);
        }
    }
}

// ---------------- K2: per-image threshold bin via suffix scan ----------------
__global__ __launch_bounds__(256) void k_findT(const int* __restrict__ hist,
                                               int* __restrict__ Tarr) {
    int b = blockIdx.x, tid = threadIdx.x;
    __shared__ int h[NBINS];
    __shared__ int s_T;
    if (tid == 0) s_T = 0;
    #pragma unroll
    for (int k = 0; k < 4; ++k) h[tid + k * 256] = hist[b * NBINS + tid + k * 256];
    __syncthreads();
    for (int off = 1; off < NBINS; off <<= 1) {
        int tmp[4];
        #pragma unroll
        for (int k = 0; k < 4; ++k) {
            int idx = tid + k * 256;
            tmp[k] = (idx + off < NBINS) ? h[idx + off] : 0;
        }
        __syncthreads();
        #pragma unroll
        for (int k = 0; k < 4; ++k) h[tid + k * 256] += tmp[k];
        __syncthreads();
    }
    #pragma unroll
    for (int k = 0; k < 4; ++k) {
        int idx = tid + k * 256;
        int S = h[idx];
        int Sn = (idx + 1 < NBINS) ? h[idx + 1] : 0;
        if (S >= KTOP && Sn < KTOP) s_T = idx;   // unique (suffix monotone)
    }
    __syncthreads();
    if (tid == 0) Tarr[b] = s_T;
}

// ---------------- K3: gather survivors, one atomic per block ----------------
__global__ __launch_bounds__(256) void k_gather(const float* __restrict__ score,
                                                const int* __restrict__ Tarr,
                                                ull* __restrict__ keys,
                                                int* __restrict__ cnt) {
    int b = blockIdx.y;
    int n = blockIdx.x * 256 + threadIdx.x;
    int tid = threadIdx.x;
    __shared__ int wbase[4];
    __shared__ int sT;
    if (tid == 0) sT = Tarr[b];
    __syncthreads();
    bool want = false;
    float s = 0.0f;
    if (n < NCAND) {
        s = score[b * NCAND + n];
        if (s > CONF) {
            int bin = (int)((s - CONF) * HSCALE);
            bin = bin < 0 ? 0 : (bin > NBINS - 1 ? NBINS - 1 : bin);
            want = (bin >= sT);
        }
    }
    ull m = __ballot(want);
    int lane = tid & 63, widx = tid >> 6;
    if (lane == 0) wbase[widx] = __popcll(m);
    __syncthreads();
    if (tid == 0) {
        int t0 = wbase[0], t1 = wbase[1], t2 = wbase[2], t3 = wbase[3];
        int tot = t0 + t1 + t2 + t3;
        int b0 = tot ? atomicAdd(&cnt[b * CNT_STRIDE], tot) : 0;
        wbase[0] = b0; wbase[1] = b0 + t0; wbase[2] = b0 + t0 + t1; wbase[3] = b0 + t0 + t1 + t2;
    }
    __syncthreads();
    if (want) {
        int pos = wbase[widx] + __popcll(m & ((1ULL << lane) - 1ULL));
        if (pos < CAP) {
            unsigned int sb = __float_as_uint(s);
            keys[b * CAP + pos] = ((ull)(~sb) << 32) | (unsigned)n;
        }
    }
}

// ---------------- K4: per-image bitonic sort (P=1024 or 2048) + emit top-K ----
__global__ __launch_bounds__(1024) void k_sort(const float* __restrict__ pred,
                                               const ull* __restrict__ keys,
                                               const int* __restrict__ cnt,
                                               int* __restrict__ topidx,
                                               float* __restrict__ topsc,
                                               int* __restrict__ topcls,
                                               float* __restrict__ boxes) {
    int b = blockIdx.x, tid = threadIdx.x;
    __shared__ ull sbuf[CAP];
    __shared__ int s_C2;
    if (tid == 0) {
        int c = cnt[b * CNT_STRIDE];
        s_C2 = c > CAP ? CAP : c;
    }
    __syncthreads();
    int C2 = s_C2;
    unsigned P = (C2 <= 1024) ? 1024u : 2048u;
    sbuf[tid] = keys[b * CAP + tid];
    if (P > 1024) sbuf[tid + 1024] = keys[b * CAP + tid + 1024];
    __syncthreads();
    for (unsigned k = 2; k <= P; k <<= 1) {
        for (unsigned j = k >> 1; j > 0; j >>= 1) {
            for (unsigned t = tid; t < P; t += 1024) {
                unsigned ixj = t ^ j;
                if (ixj > t) {
                    ull a = sbuf[t], bb = sbuf[ixj];
                    if ((a > bb) == ((t & k) == 0)) { sbuf[t] = bb; sbuf[ixj] = a; }
                }
            }
            __syncthreads();
        }
    }
    if (tid < KTOP) {
        int o = b * KTOP + tid;
        if (tid < C2) {
            ull key = sbuf[tid];
            int n = (int)(key & 0xFFFFFFFFULL);
            float s = __uint_as_float(~(unsigned int)(key >> 32));
            const float* row = pred + ((size_t)b * NCAND + n) * PREDC;
            float cx = row[0], cy = row[1], w = row[2], h = row[3];
            float obj = row[4];
            float best = -1.0f; int bj = 0;
            for (int c = 0; c < NCLS; ++c) {
                float v = row[5 + c] * obj;
                if (v > best) { best = v; bj = c; }
            }
            topidx[o] = n; topsc[o] = s; topcls[o] = bj;
            ((float4*)boxes)[o] = make_float4(cx - w * 0.5f, cy - h * 0.5f,
                                              cx + w * 0.5f, cy + h * 0.5f);
        } else {
            topidx[o] = 0; topsc[o] = -1.0f; topcls[o] = 0;
            ((float4*)boxes)[o] = make_float4(0.f, 0.f, 0.f, 0.f);
        }
    }
}

// ---------------- K5: IoU bitmask (j>i, iou>thr) + nz bitmap ----------------
__global__ __launch_bounds__(256) void k_iou(const float* __restrict__ boxes,
                                             ull* __restrict__ M,
                                             ull* __restrict__ nzw) {
    #pragma clang fp contract(off)
    int g = blockIdx.x * 256 + threadIdx.x;   // 16*1000*16 = 256000
    int w = g & 15;
    int bi = g >> 4;                          // 0..15999
    int i = bi % KTOP;
    int b = bi / KTOP;
    int j0 = w * 64;
    if (j0 + 63 <= i) {                       // whole block strictly j<=i -> zero
        M[(size_t)bi * 16 + w] = 0ULL;
        return;
    }
    const float4* bx = (const float4*)boxes + (size_t)b * KTOP;
    float4 A = bx[i];
    float areaA = (A.z - A.x) * (A.w - A.y);
    ull word = 0;
    int jend = j0 + 64; if (jend > KTOP) jend = KTOP;
    #pragma unroll 4
    for (int j = j0; j < jend; ++j) {
        float4 Bb = bx[j];
        float areaB = (Bb.z - Bb.x) * (Bb.w - Bb.y);
        float lx = fmaxf(A.x, Bb.x), ly = fmaxf(A.y, Bb.y);
        float rx = fminf(A.z, Bb.z), ry = fminf(A.w, Bb.w);
        float ww = rx - lx; ww = ww > 0.f ? ww : 0.f;
        float hh = ry - ly; hh = hh > 0.f ? hh : 0.f;
        float inter = ww * hh;
        float denom = ((areaA + areaB) - inter) + 1e-9f;
        float iou = inter / denom;
        if (j > i && iou > 0.45f) word |= 1ULL << (j - j0);
    }
    M[(size_t)bi * 16 + w] = word;
    if (word) atomicOr(&nzw[b * 16 + (i >> 6)], 1ULL << (i & 63));
}

// ---------------- K6: NMS (vcc-test serial chain) + top-300 outputs ----------------
__global__ __launch_bounds__(256) void k_nms_out(const ull* __restrict__ M,
                                                 const ull* __restrict__ nzw,
                                                 const int* __restrict__ cnt,
                                                 const float* __restrict__ logits,
                                                 const int* __restrict__ topidx,
                                                 const float* __restrict__ topsc,
                                                 const int* __restrict__ topcls,
                                                 const float* __restrict__ boxes,
                                                 float* __restrict__ out) {
    __shared__ ull mrows[NMS_CHUNK * 16];   // 56,320 B
    __shared__ int nzlist[KTOP];            // 4,000 B
    __shared__ ull s_nzw[16];
    __shared__ ull s_keep[16];
    __shared__ int s_nnz;
    __shared__ int kept_r[MAXDET];
    __shared__ int kept_n[MAXDET];
    __shared__ int s_kc;
    int b = blockIdx.x, tid = threadIdx.x;
    if (tid < 16) s_nzw[tid] = nzw[b * 16 + tid];
    __syncthreads();
    if (tid < 16) {
        int pre = 0;
        for (int u = 0; u < tid; ++u) pre += __popcll(s_nzw[u]);
        ull wv = s_nzw[tid];
        int ofs = pre;
        while (wv) {
            int bit = __builtin_ctzll(wv);
            nzlist[ofs++] = tid * 64 + bit;
            wv &= wv - 1;
        }
        if (tid == 15) s_nnz = ofs;
    }
    __syncthreads();
    int nnz = s_nnz;
    int kc0 = cnt[b * CNT_STRIDE]; if (kc0 > KTOP) kc0 = KTOP;
    const ull* Mb = M + (size_t)b * KTOP * 16;
    // each lane (tid<64) holds word w = tid&15; 4 identical replicas per word
    ull supp = 0;
    {
        int w = tid & 15, lo = w * 64;
        if (kc0 <= lo) supp = ~0ULL;
        else if (kc0 >= lo + 64) supp = 0ULL;
        else supp = (~0ULL) << (kc0 - lo);
    }
    for (int c0 = 0; c0 < nnz; c0 += NMS_CHUNK) {
        int cn = nnz - c0; if (cn > NMS_CHUNK) cn = NMS_CHUNK;
        // cooperative bulk load of chunk rows into LDS (coalesced 128B/row)
        for (int u = tid; u < cn * 16; u += 256)
            mrows[u] = Mb[(size_t)nzlist[c0 + (u >> 4)] * 16 + (u & 15)];
        __syncthreads();
        if (tid < 64) {
            int w = tid & 15;
            for (int k = 0; k < cn; k += 8) {
                ull mb[8]; int ii[8];
                #pragma unroll
                for (int d = 0; d < 8; ++d) {
                    int kk = k + d; kk = kk < cn ? kk : cn - 1;
                    mb[d] = mrows[kk * 16 + w];
                    ii[d] = nzlist[c0 + kk];
                }
                #pragma unroll
                for (int d = 0; d < 8; ++d) {
                    if (k + d < cn) {
                        int i = ii[d];
                        // suppressed-bit lives on lanes with w == i>>6; test via vcc
                        bool sb = (w == (i >> 6)) && ((supp >> (i & 63)) & 1ULL);
                        if (__ballot(sb) == 0ULL) supp |= mb[d];   // alive
                    }
                }
            }
        }
        __syncthreads();
    }
    if (tid < 16) s_keep[tid] = ~supp;   // lanes 0..15 hold words 0..15
    __syncthreads();
    // ---- output phase (all 256 threads) ----
    if (tid < 16) {
        int pre = 0;
        for (int u = 0; u < tid; ++u) pre += __popcll(s_keep[u]);
        ull wv = s_keep[tid];
        int rank = pre;
        while (wv) {
            int bit = __builtin_ctzll(wv);
            if (rank < MAXDET) kept_r[rank] = tid * 64 + bit;
            rank++;
            wv &= wv - 1;
        }
        if (tid == 15) s_kc = rank < MAXDET ? rank : MAXDET;
    }
    __syncthreads();
    int kc = s_kc;
    for (int s = tid; s < MAXDET; s += 256)
        if (s < kc) kept_n[s] = topidx[b * KTOP + kept_r[s]];
    __syncthreads();
    float* det = out;                                        // [16][300][6]
    float* mask_o = out + BATCH * MAXDET * 6;                // [16][300]
    float* lgo = out + BATCH * MAXDET * 6 + BATCH * MAXDET;  // [16][300][80]
    for (int idx = tid; idx < MAXDET * 6; idx += 256) {
        int s = idx / 6, col = idx % 6;
        float v = 0.f;
        if (s < kc) {
            int o = b * KTOP + kept_r[s];
            if (col < 4) v = boxes[o * 4 + col];
            else if (col == 4) v = topsc[o];
            else v = (float)topcls[o];
        }
        det[b * MAXDET * 6 + idx] = v;
    }
    for (int s = tid; s < MAXDET; s += 256)
        mask_o[b * MAXDET + s] = (s < kc) ? 1.0f : 0.0f;
    for (int idx = tid; idx < MAXDET * NCLS; idx += 256) {
        int s = idx / NCLS, c = idx % NCLS;
        float v = 0.f;
        if (s < kc) v = logits[((size_t)b * NCAND + kept_n[s]) * NCLS + c];
        lgo[b * MAXDET * NCLS + idx] = v;
    }
}

extern "C" void kernel_launch(void* const* d_in, const int* in_sizes, int n_in,
                              void* d_out, int out_size, void* d_ws, size_t ws_size,
                              hipStream_t stream) {
    (void)in_sizes; (void)n_in; (void)out_size; (void)ws_size;
    const float* pred = (const float*)d_in[0];
    const float* logits = (const float*)d_in[1];
    float* out = (float*)d_out;
    char* ws = (char*)d_ws;

    // workspace layout (bytes). Region A is time-shared:
    //   score/hist/Tarr live K0..K3; M (2,048,000) overlays them, live K5..K6.
    float* score  = (float*)(ws + 0);                    // 1,612,800
    int*   hist   = (int*)(ws + 1612800);                // 65,536
    int*   Tarr   = (int*)(ws + 1678336);                // 64
    ull*   M      = (ull*)(ws + 0);                      // 2,048,000 (overlay)
    ull*   keys   = (ull*)(ws + 2048000);                // 262,144
    int*   cnt    = (int*)(ws + 2310144);                // 1,024 (16 imgs x 64B)
    int*   topidx = (int*)(ws + 2311168);                // 64,000
    float* topsc  = (float*)(ws + 2375168);              // 64,000
    int*   topcls = (int*)(ws + 2439168);                // 64,000
    float* boxes  = (float*)(ws + 2503168);              // 256,000 (16B aligned)
    ull*   nzw    = (ull*)(ws + 2759168);                // 2,048  (total 2,761,216)

    const int nrows = BATCH * NCAND;                     // 403200
    k_init<<<128, 256, 0, stream>>>(hist, keys, cnt, nzw);
    k_score<<<nrows / TILE_ROWS, 256, 0, stream>>>(pred, score, hist);
    k_findT<<<BATCH, 256, 0, stream>>>(hist, Tarr);
    k_gather<<<dim3((NCAND + 255) / 256, BATCH), 256, 0, stream>>>(score, Tarr, keys, cnt);
    k_sort<<<BATCH, 1024, 0, stream>>>(pred, keys, cnt, topidx, topsc, topcls, boxes);
    k_iou<<<(BATCH * KTOP * 16) / 256, 256, 0, stream>>>(boxes, M, nzw);
    k_nms_out<<<BATCH, 256, 0, stream>>>(M, nzw, cnt, logits, topidx, topsc, topcls, boxes, out);
}